// Round 3
// baseline (2937.776 us; speedup 1.0000x reference)
//
#include <hip/hip_runtime.h>

#define HIDDEN  64
#define T_STEPS 2048
#define N_INPUT 5
#define DT      0.1f
#define LN_EPS  1e-5f

// pin a value into a VGPR: compiler can no longer rematerialize the load
#define PIN(v) asm volatile("" : "+v"(v))

// broadcast lane `l`'s value of v to all lanes (SGPR result -> fmac scalar operand)
__device__ __forceinline__ float bcast(float v, int l) {
    return __uint_as_float(__builtin_amdgcn_readlane(__float_as_uint(v), l));
}

// single-instruction xor-swizzle within 32-lane halves (BitMode: xor<<10 | 0x1F)
template <int XMASK>
__device__ __forceinline__ float swz_xor(float v) {
    return __uint_as_float(
        __builtin_amdgcn_ds_swizzle(__float_as_uint(v), (XMASK << 10) | 0x1F));
}

// cross-half exchange (lane ^ 32); addr32 = ((lane^32)<<2) hoisted by caller
__device__ __forceinline__ float bperm(int addr32, float v) {
    return __uint_as_float(__builtin_amdgcn_ds_bpermute(addr32, __float_as_uint(v)));
}

// fast tanh: (e-1)/(e+1), e = 2^(2*log2e*y); y pre-clamped so e is finite
__device__ __forceinline__ float fast_tanh(float y) {
    y = fminf(fmaxf(y, -15.0f), 15.0f);
    const float e = exp2f(y * 2.885390081777927f);  // 2*log2(e)
    return (e - 1.0f) * __builtin_amdgcn_rcpf(e + 1.0f);
}

__global__ __launch_bounds__(256, 4) void hlnn_main(
    const float* __restrict__ x, const float* __restrict__ W_in,
    const float* __restrict__ b_in, const float* __restrict__ tau_param,
    const float* __restrict__ W_rec, const float* __restrict__ ln1_w,
    const float* __restrict__ ln1_b, const float* __restrict__ ln2_w,
    const float* __restrict__ ln2_b, const float* __restrict__ head_W,
    const float* __restrict__ head_b, float* __restrict__ out, int B)
{
    const int lane = threadIdx.x & 63;
    const int wav  = threadIdx.x >> 6;
    const int b    = blockIdx.x * 4 + wav;         // one wave per batch row
    const int addr32 = ((lane ^ 32) & 63) << 2;    // hoisted bpermute address

    // ---- per-lane constants (lane j owns hidden unit j), pinned into VGPRs ----
    float wcol[HIDDEN];                            // W_rec[:, lane]
#pragma unroll
    for (int i = 0; i < HIDDEN; ++i) wcol[i] = W_rec[i * HIDDEN + lane];
#pragma unroll
    for (int i = 0; i < HIDDEN; ++i) PIN(wcol[i]);

    float win[N_INPUT];                            // W_in[:, lane]
#pragma unroll
    for (int s = 0; s < N_INPUT; ++s) win[s] = W_in[s * HIDDEN + lane];
#pragma unroll
    for (int s = 0; s < N_INPUT; ++s) PIN(win[s]);

    float binv = b_in[lane];
    float l1w  = ln1_w[lane], l1b = ln1_b[lane];
    const float tau  = log1pf(expf(tau_param[lane]));   // softplus
    float decay = 1.0f - DT / tau;                      // h*(1 - dt/tau) + dt*f
    PIN(binv); PIN(l1w); PIN(l1b); PIN(decay);

    float h = 0.0f;
    // wave-uniform x pointer -> scalar (SMEM) loads
    const int bu = __builtin_amdgcn_readfirstlane(b);
    const float* xb = x + (size_t)bu * (T_STEPS * N_INPUT);

    float xs[N_INPUT];
#pragma unroll
    for (int s = 0; s < N_INPUT; ++s) xs[s] = xb[s];

#pragma unroll 2
    for (int t = 0; t < T_STEPS; ++t) {
        // prefetch next step's 5 input scalars (wave-uniform -> s_load)
        const int tn = (t + 1 < T_STEPS) ? (t + 1) : t;
        float xn[N_INPUT];
#pragma unroll
        for (int s = 0; s < N_INPUT; ++s) xn[s] = xb[(size_t)tn * N_INPUT + s];

        // pre[j] = b_in[j] + x_t . W_in[:,j] + sum_i h[i] * W_rec[i][j]
        float p0 = binv, p1 = 0.0f, p2 = 0.0f, p3 = 0.0f;
#pragma unroll
        for (int s = 0; s < N_INPUT; ++s) p0 = fmaf(xs[s], win[s], p0);
#pragma unroll
        for (int i = 0; i < HIDDEN; i += 4) {
            p0 = fmaf(bcast(h, i + 0), wcol[i + 0], p0);
            p1 = fmaf(bcast(h, i + 1), wcol[i + 1], p1);
            p2 = fmaf(bcast(h, i + 2), wcol[i + 2], p2);
            p3 = fmaf(bcast(h, i + 3), wcol[i + 3], p3);
        }
        const float pre = (p0 + p1) + (p2 + p3);

        // LayerNorm reduction: 5 xor-swizzles within halves + 1 cross-half bpermute
        float sum = pre, sumsq = pre * pre;
        sum += swz_xor<1>(sum);   sumsq += swz_xor<1>(sumsq);
        sum += swz_xor<2>(sum);   sumsq += swz_xor<2>(sumsq);
        sum += swz_xor<4>(sum);   sumsq += swz_xor<4>(sumsq);
        sum += swz_xor<8>(sum);   sumsq += swz_xor<8>(sumsq);
        sum += swz_xor<16>(sum);  sumsq += swz_xor<16>(sumsq);
        sum += bperm(addr32, sum);
        sumsq += bperm(addr32, sumsq);

        const float mu   = sum * (1.0f / 64.0f);
        float var        = fmaf(mu, -mu, sumsq * (1.0f / 64.0f));
        var              = fmaxf(var, 0.0f);
        const float rstd = __builtin_amdgcn_rsqf(var + LN_EPS);

        const float f = fast_tanh(fmaf((pre - mu) * rstd, l1w, l1b));
        h = fmaf(decay, h, DT * f);
        h = fminf(fmaxf(h, -10.0f), 10.0f);

#pragma unroll
        for (int s = 0; s < N_INPUT; ++s) xs[s] = xn[s];
    }

    // ---- epilogue: LN2 + 5x4 heads (once; cost negligible) ----
    float sum = h, sumsq = h * h;
    sum += swz_xor<1>(sum);   sumsq += swz_xor<1>(sumsq);
    sum += swz_xor<2>(sum);   sumsq += swz_xor<2>(sumsq);
    sum += swz_xor<4>(sum);   sumsq += swz_xor<4>(sumsq);
    sum += swz_xor<8>(sum);   sumsq += swz_xor<8>(sumsq);
    sum += swz_xor<16>(sum);  sumsq += swz_xor<16>(sumsq);
    sum += bperm(addr32, sum);
    sumsq += bperm(addr32, sumsq);

    const float mu   = sum * (1.0f / 64.0f);
    float var        = fmaf(mu, -mu, sumsq * (1.0f / 64.0f));
    var              = fmaxf(var, 0.0f);
    const float rstd = __builtin_amdgcn_rsqf(var + LN_EPS);
    const float hn   = fmaf((h - mu) * rstd, ln2_w[lane], ln2_b[lane]);

    float myout = 0.0f;
#pragma unroll
    for (int o = 0; o < 20; ++o) {
        float p = hn * head_W[o * HIDDEN + lane];
        p += swz_xor<1>(p);
        p += swz_xor<2>(p);
        p += swz_xor<4>(p);
        p += swz_xor<8>(p);
        p += swz_xor<16>(p);
        p += bperm(addr32, p);
        if (lane == o) myout = p + head_b[o];
    }
    if (lane < 20) {
        const int k = lane >> 2, a = lane & 3;     // out[k][b][a], shape (5,B,4)
        out[(size_t)k * B * 4 + (size_t)b * 4 + a] = myout;
    }
}

extern "C" void kernel_launch(void* const* d_in, const int* in_sizes, int n_in,
                              void* d_out, int out_size, void* d_ws, size_t ws_size,
                              hipStream_t stream) {
    const float* x         = (const float*)d_in[0];
    const float* W_in      = (const float*)d_in[1];
    const float* b_in      = (const float*)d_in[2];
    const float* tau_param = (const float*)d_in[3];
    const float* W_rec     = (const float*)d_in[4];
    const float* ln1_w     = (const float*)d_in[5];
    const float* ln1_b     = (const float*)d_in[6];
    const float* ln2_w     = (const float*)d_in[7];
    const float* ln2_b     = (const float*)d_in[8];
    const float* head_W    = (const float*)d_in[9];
    const float* head_b    = (const float*)d_in[10];

    const int B = in_sizes[0] / (T_STEPS * N_INPUT);   // 4096
    dim3 grid(B / 4), block(256);                      // one wave per row
    hipLaunchKernelGGL(hlnn_main, grid, block, 0, stream,
                       x, W_in, b_in, tau_param, W_rec, ln1_w, ln1_b,
                       ln2_w, ln2_b, head_W, head_b, (float*)d_out, B);
}

// Round 4
// 1687.160 us; speedup vs baseline: 1.7413x; 1.7413x over previous
//
#include <hip/hip_runtime.h>

#define HIDDEN  64
#define T_STEPS 2048
#define N_INPUT 5
#define DT      0.1f
#define LN_EPS  1e-5f
#define ROWS    16                     // batch rows per block (MFMA N)
#define TANH_K  2.885390081777927f     // 2*log2(e)

typedef short bf16x8 __attribute__((ext_vector_type(8)));
typedef float f32x4  __attribute__((ext_vector_type(4)));

union FragU { uint4 u4; unsigned int u[4]; unsigned short us[8]; bf16x8 v; };

__device__ __forceinline__ unsigned short bf16_trunc(float f) {
    return (unsigned short)(__float_as_uint(f) >> 16);
}
__device__ __forceinline__ float bf16_hi_f32(float f) {
    return __uint_as_float(__float_as_uint(f) & 0xFFFF0000u);
}
// pack bf16-trunc of two floats into one dword (lo half = f0, hi half = f1)
__device__ __forceinline__ unsigned int bf16_pack2(float f0, float f1) {
    return (__float_as_uint(f0) >> 16) | (__float_as_uint(f1) & 0xFFFF0000u);
}
template <int XMASK>
__device__ __forceinline__ float swz_xor(float v) {   // xor within 32-lane halves
    return __uint_as_float(
        __builtin_amdgcn_ds_swizzle(__float_as_uint(v), (XMASK << 10) | 0x1F));
}
__device__ __forceinline__ float bperm(int addr32, float v) {  // lane^32 exchange
    return __uint_as_float(__builtin_amdgcn_ds_bpermute(addr32, __float_as_uint(v)));
}

#define MFMA(A, B, C) __builtin_amdgcn_mfma_f32_16x16x32_bf16((A), (B), (C), 0, 0, 0)

__global__ __launch_bounds__(256, 1) void hlnn_mfma(
    const float* __restrict__ x, const float* __restrict__ W_in,
    const float* __restrict__ b_in, const float* __restrict__ tau_param,
    const float* __restrict__ W_rec, const float* __restrict__ ln1_w,
    const float* __restrict__ ln1_b, const float* __restrict__ ln2_w,
    const float* __restrict__ ln2_b, const float* __restrict__ head_W,
    const float* __restrict__ head_b, float* __restrict__ out, int Btot)
{
    const int tid  = threadIdx.x;
    const int lane = tid & 63;
    const int w    = tid >> 6;        // wave id = hidden 16-col tile
    const int r    = lane & 15;       // batch row within group (MFMA n / A m)
    const int q    = lane >> 4;       // quad
    const int g    = blockIdx.x;      // 16-row group
    const int addr32 = ((lane ^ 32) & 63) << 2;

    // h transposed transport: [row][hidden] bf16, 72-ushort (144B) row stride
    __shared__ unsigned short hHi[ROWS][72];
    __shared__ unsigned short hLo[ROWS][72];
    __shared__ float stats[ROWS][12];          // [row][wave*2 + {sum,sq}]
    __shared__ float hnbuf[ROWS][68];          // epilogue LN2 output

    // ---- static A fragments: A[m=lane&15][k=q*8+j] = W_rec[k][16w+m], split hi/lo
    FragU A_hi[2], A_lo[2];
    const int cfrag = 16 * w + r;              // global hidden col of this lane's A
#pragma unroll
    for (int kk = 0; kk < 2; ++kk)
#pragma unroll
        for (int j = 0; j < 8; ++j) {
            const float wv = W_rec[(kk * 32 + q * 8 + j) * HIDDEN + cfrag];
            A_hi[kk].us[j] = bf16_trunc(wv);
            A_lo[kk].us[j] = bf16_trunc(wv - bf16_hi_f32(wv));
        }
    FragU Ax_hi, Ax_lo;                        // W_in^T, K=32 (rows >=5 zero)
#pragma unroll
    for (int j = 0; j < 8; ++j) {
        const int kg = q * 8 + j;
        const float wv = (kg < N_INPUT) ? W_in[kg * HIDDEN + cfrag] : 0.0f;
        Ax_hi.us[j] = bf16_trunc(wv);
        Ax_lo.us[j] = bf16_trunc(wv - bf16_hi_f32(wv));
    }

    // ---- per-lane elementwise constants: this lane owns (c = 16w+4q+e, row r)
    float l1w4[4], l1b4[4], dec4[4], ln2w4[4], ln2b4[4];
    f32x4 cinit;
#pragma unroll
    for (int e = 0; e < 4; ++e) {
        const int c = 16 * w + 4 * q + e;
        l1w4[e]  = ln1_w[c];  l1b4[e] = ln1_b[c];
        const float tp  = tau_param[c];
        const float tau = (tp > 20.0f) ? tp : log1pf(expf(tp));   // softplus
        dec4[e]  = 1.0f - DT / tau;
        ln2w4[e] = ln2_w[c];  ln2b4[e] = ln2_b[c];
        cinit[e] = b_in[c];                                       // MFMA C-init
    }

    const float* xrow = x + (size_t)(g * ROWS + r) * T_STEPS * N_INPUT;

    // initial x frag (t=0); only q==0 lanes carry data (k<8)
    float xn[N_INPUT];
#pragma unroll
    for (int s = 0; s < N_INPUT; ++s) xn[s] = xrow[s];
    FragU Bx_hi, Bx_lo;
    {
        float x0 = (q == 0) ? xn[0] : 0.f, x1 = (q == 0) ? xn[1] : 0.f;
        float x2 = (q == 0) ? xn[2] : 0.f, x3 = (q == 0) ? xn[3] : 0.f;
        float x4 = (q == 0) ? xn[4] : 0.f;
        Bx_hi.u[0] = bf16_pack2(x0, x1); Bx_hi.u[1] = bf16_pack2(x2, x3);
        Bx_hi.u[2] = bf16_pack2(x4, 0.f); Bx_hi.u[3] = 0u;
        float l0 = x0 - bf16_hi_f32(x0), l1 = x1 - bf16_hi_f32(x1);
        float l2 = x2 - bf16_hi_f32(x2), l3 = x3 - bf16_hi_f32(x3);
        float l4 = x4 - bf16_hi_f32(x4);
        Bx_lo.u[0] = bf16_pack2(l0, l1); Bx_lo.u[1] = bf16_pack2(l2, l3);
        Bx_lo.u[2] = bf16_pack2(l4, 0.f); Bx_lo.u[3] = 0u;
    }

    FragU Bh[2], Bl[2];                        // h^T B-frags (h0 = 0)
    Bh[0].u4 = make_uint4(0,0,0,0); Bh[1].u4 = make_uint4(0,0,0,0);
    Bl[0].u4 = make_uint4(0,0,0,0); Bl[1].u4 = make_uint4(0,0,0,0);
    float h[4] = {0.f, 0.f, 0.f, 0.f};         // fp32 state: (c=16w+4q+e, row r)

    for (int t = 0; t < T_STEPS; ++t) {
        // prefetch next step's x (5 scalars per row; hidden under MFMA+LN)
        const size_t toff = (size_t)((t + 1 < T_STEPS) ? (t + 1) : t) * N_INPUT;
        float xf[N_INPUT];
#pragma unroll
        for (int s = 0; s < N_INPUT; ++s) xf[s] = xrow[toff + s];

        // pre^T = b_in + W_in^T.x^T + W_rec^T.h^T   (split-bf16, 9 MFMAs)
        f32x4 acc = MFMA(Ax_hi.v, Bx_hi.v, cinit);
        acc = MFMA(Ax_hi.v, Bx_lo.v, acc);
        acc = MFMA(Ax_lo.v, Bx_hi.v, acc);
        acc = MFMA(A_hi[0].v, Bh[0].v, acc);
        acc = MFMA(A_hi[0].v, Bl[0].v, acc);
        acc = MFMA(A_lo[0].v, Bh[0].v, acc);
        acc = MFMA(A_hi[1].v, Bh[1].v, acc);
        acc = MFMA(A_hi[1].v, Bl[1].v, acc);
        acc = MFMA(A_lo[1].v, Bh[1].v, acc);

        // LN stats: lane's 4 values all belong to row r -> local + q-reduce
        float s1 = (acc[0] + acc[1]) + (acc[2] + acc[3]);
        float s2 = fmaf(acc[0], acc[0], fmaf(acc[1], acc[1],
                   fmaf(acc[2], acc[2], acc[3] * acc[3])));
        s1 += swz_xor<16>(s1);  s2 += swz_xor<16>(s2);
        s1 += bperm(addr32, s1); s2 += bperm(addr32, s2);

        if (q == 0) *(float2*)&stats[r][2 * w] = make_float2(s1, s2);
        __syncthreads();
        const float sum = (stats[r][0] + stats[r][2]) + (stats[r][4] + stats[r][6]);
        const float ssq = (stats[r][1] + stats[r][3]) + (stats[r][5] + stats[r][7]);

        const float mu   = sum * (1.0f / 64.0f);
        float var        = fmaf(mu, -mu, ssq * (1.0f / 64.0f));
        var              = fmaxf(var, 0.0f);
        const float rstd = __builtin_amdgcn_rsqf(var + LN_EPS);

        // f = tanh(LN(pre)); h = clip(decay*h + dt*f)
#pragma unroll
        for (int e = 0; e < 4; ++e) {
            float y = fmaf((acc[e] - mu) * rstd, l1w4[e], l1b4[e]);
            y = fminf(fmaxf(y, -15.0f), 15.0f);
            const float ex = exp2f(y * TANH_K);
            const float f  = (ex - 1.0f) * __builtin_amdgcn_rcpf(ex + 1.0f);
            float hv = fmaf(dec4[e], h[e], DT * f);
            h[e] = fminf(fmaxf(hv, -10.0f), 10.0f);
        }

        // split h -> bf16 hi/lo, write transposed to LDS (b64, conflict-free)
        const int c0 = 16 * w + 4 * q;
        {
            const unsigned int hi01 = bf16_pack2(h[0], h[1]);
            const unsigned int hi23 = bf16_pack2(h[2], h[3]);
            const float l0 = h[0] - bf16_hi_f32(h[0]), l1v = h[1] - bf16_hi_f32(h[1]);
            const float l2 = h[2] - bf16_hi_f32(h[2]), l3v = h[3] - bf16_hi_f32(h[3]);
            *(uint2*)&hHi[r][c0] = make_uint2(hi01, hi23);
            *(uint2*)&hLo[r][c0] = make_uint2(bf16_pack2(l0, l1v), bf16_pack2(l2, l3v));
        }
        __syncthreads();

        // B-frags for next step: lane reads row r, k = kk*32 + q*8 .. +7
#pragma unroll
        for (int kk = 0; kk < 2; ++kk) {
            Bh[kk].u4 = *(const uint4*)&hHi[r][kk * 32 + q * 8];
            Bl[kk].u4 = *(const uint4*)&hLo[r][kk * 32 + q * 8];
        }

        // convert prefetched x -> next Bx frags
        {
            float x0 = (q == 0) ? xf[0] : 0.f, x1 = (q == 0) ? xf[1] : 0.f;
            float x2 = (q == 0) ? xf[2] : 0.f, x3 = (q == 0) ? xf[3] : 0.f;
            float x4 = (q == 0) ? xf[4] : 0.f;
            Bx_hi.u[0] = bf16_pack2(x0, x1); Bx_hi.u[1] = bf16_pack2(x2, x3);
            Bx_hi.u[2] = bf16_pack2(x4, 0.f); Bx_hi.u[3] = 0u;
            const float l0 = x0 - bf16_hi_f32(x0), l1v = x1 - bf16_hi_f32(x1);
            const float l2 = x2 - bf16_hi_f32(x2), l3v = x3 - bf16_hi_f32(x3);
            const float l4 = x4 - bf16_hi_f32(x4);
            Bx_lo.u[0] = bf16_pack2(l0, l1v); Bx_lo.u[1] = bf16_pack2(l2, l3v);
            Bx_lo.u[2] = bf16_pack2(l4, 0.f); Bx_lo.u[3] = 0u;
        }
    }

    // ---- epilogue: LN2 on final h, then 5x4 heads ----
    {
        float s1 = (h[0] + h[1]) + (h[2] + h[3]);
        float s2 = fmaf(h[0], h[0], fmaf(h[1], h[1], fmaf(h[2], h[2], h[3] * h[3])));
        s1 += swz_xor<16>(s1);  s2 += swz_xor<16>(s2);
        s1 += bperm(addr32, s1); s2 += bperm(addr32, s2);
        if (q == 0) *(float2*)&stats[r][2 * w] = make_float2(s1, s2);
        __syncthreads();
        const float sum = (stats[r][0] + stats[r][2]) + (stats[r][4] + stats[r][6]);
        const float ssq = (stats[r][1] + stats[r][3]) + (stats[r][5] + stats[r][7]);
        const float mu   = sum * (1.0f / 64.0f);
        float var        = fmaf(mu, -mu, ssq * (1.0f / 64.0f));
        var              = fmaxf(var, 0.0f);
        const float rstd = __builtin_amdgcn_rsqf(var + LN_EPS);
        const int c0 = 16 * w + 4 * q;
        float hn0 = fmaf((h[0] - mu) * rstd, ln2w4[0], ln2b4[0]);
        float hn1 = fmaf((h[1] - mu) * rstd, ln2w4[1], ln2b4[1]);
        float hn2 = fmaf((h[2] - mu) * rstd, ln2w4[2], ln2b4[2]);
        float hn3 = fmaf((h[3] - mu) * rstd, ln2w4[3], ln2b4[3]);
        *(float4*)&hnbuf[r][c0] = make_float4(hn0, hn1, hn2, hn3);
    }
    __syncthreads();

    for (int o = tid; o < ROWS * 20; o += 256) {
        const int rr = o / 20, ka = o % 20;
        float p = head_b[ka];
#pragma unroll
        for (int c = 0; c < HIDDEN; ++c)
            p = fmaf(hnbuf[rr][c], head_W[ka * HIDDEN + c], p);
        const int k = ka >> 2, a = ka & 3;     // out[k][b][a], shape (5,B,4)
        out[(size_t)k * Btot * 4 + (size_t)(g * ROWS + rr) * 4 + a] = p;
    }
}

extern "C" void kernel_launch(void* const* d_in, const int* in_sizes, int n_in,
                              void* d_out, int out_size, void* d_ws, size_t ws_size,
                              hipStream_t stream) {
    const float* x         = (const float*)d_in[0];
    const float* W_in      = (const float*)d_in[1];
    const float* b_in      = (const float*)d_in[2];
    const float* tau_param = (const float*)d_in[3];
    const float* W_rec     = (const float*)d_in[4];
    const float* ln1_w     = (const float*)d_in[5];
    const float* ln1_b     = (const float*)d_in[6];
    const float* ln2_w     = (const float*)d_in[7];
    const float* ln2_b     = (const float*)d_in[8];
    const float* head_W    = (const float*)d_in[9];
    const float* head_b    = (const float*)d_in[10];

    const int B = in_sizes[0] / (T_STEPS * N_INPUT);   // 4096
    dim3 grid(B / ROWS), block(256);                   // 256 blocks x 4 waves
    hipLaunchKernelGGL(hlnn_mfma, grid, block, 0, stream,
                       x, W_in, b_in, tau_param, W_rec, ln1_w, ln1_b,
                       ln2_w, ln2_b, head_W, head_b, (float*)d_out, B);
}